// Round 1
// baseline (77.047 us; speedup 1.0000x reference)
//
#include <hip/hip_runtime.h>
#include <math.h>

constexpr int NSEG = 128;
constexpr int P    = 512;
constexpr int D    = 64;
constexpr int KT   = 15;
constexpr int NCLS = 8;

__global__ __launch_bounds__(512, 1) void lmnn_kernel(
    const float* __restrict__ center,   // (NSEG, D)
    const float* __restrict__ outputs,  // (NSEG, P, D)
    const int*   __restrict__ labels,   // (NSEG, P)
    float* __restrict__ out)            // scalar
{
    __shared__ float s_dist[P];
    __shared__ int   s_lab[P];
    __shared__ float s_S[NCLS];
    __shared__ float s_M[NCLS];
    __shared__ int   s_cnt[NCLS];
    __shared__ float s_hb[NCLS];   // 1 + M[c]
    __shared__ float s_dc[NCLS];   // P - cnt[c]
    __shared__ float s_margin;
    __shared__ float s_pull;
    __shared__ float s_wsum[8];

    const int seg  = blockIdx.x;
    const int tid  = threadIdx.x;
    const int lane = tid & 63;
    const int wave = tid >> 6;

    // ---- load labels into LDS (coalesced) ----
    s_lab[tid] = labels[seg * P + tid];

    // ---- phase 1: dist_c[a] = ||outputs[seg,a,:] - center[seg,:]||^2 ----
    // Each wave iteration handles 4 points (1 KiB contiguous = fully coalesced).
    // Lane l covers dims [(l%16)*4, +4) of point 4g + l/16.
    const float4* c4 = reinterpret_cast<const float4*>(center + seg * D);
    const float4  cf = c4[lane & 15];

    const float4* o4 = reinterpret_cast<const float4*>(outputs + (size_t)seg * P * D);
    for (int g = wave; g < P / 4; g += 8) {
        float4 v = o4[g * 64 + lane];
        float dx = v.x - cf.x;
        float dy = v.y - cf.y;
        float dz = v.z - cf.z;
        float dw = v.w - cf.w;
        float acc = dx * dx + dy * dy + dz * dz + dw * dw;
        // reduce across the 16-lane subgroup that shares a point
        acc += __shfl_xor(acc, 1);
        acc += __shfl_xor(acc, 2);
        acc += __shfl_xor(acc, 4);
        acc += __shfl_xor(acc, 8);
        if ((lane & 15) == 0) s_dist[g * 4 + (lane >> 4)] = acc;
    }
    __syncthreads();

    // ---- phase 2: per-class first-15 stats; wave w owns class w ----
    {
        const int c = wave;
        float S = 0.0f;
        float M = -INFINITY;
        int taken = 0;   // selected so far (capped at KT)
        int total = 0;   // full class count
        for (int j = 0; j < 8; ++j) {
            const int pos = j * 64 + lane;
            const bool pred = (s_lab[pos] == c);
            const unsigned long long mask = __ballot(pred);
            const int cnt  = __popcll(mask);
            const int rank = __popcll(mask & ((1ull << lane) - 1ull));
            const bool sel = pred && (taken + rank < KT);
            float vs = sel ? s_dist[pos] : 0.0f;
            float vm = sel ? s_dist[pos] : -INFINITY;
            #pragma unroll
            for (int m = 1; m < 64; m <<= 1) {
                vs += __shfl_xor(vs, m);
                vm = fmaxf(vm, __shfl_xor(vm, m));
            }
            S += vs;
            M = fmaxf(M, vm);
            total += cnt;
            taken += cnt;
            if (taken > KT) taken = KT;
        }
        // Rare: fewer than 15 same-class members -> top_k fills with the
        // lowest-index different-class entries (all tied at -inf).
        if (total < KT) {
            const int need = KT - total;
            int t2 = 0;
            for (int j = 0; j < 8 && t2 < need; ++j) {
                const int pos = j * 64 + lane;
                const bool pred = (s_lab[pos] != c);
                const unsigned long long mask = __ballot(pred);
                const int cnt  = __popcll(mask);
                const int rank = __popcll(mask & ((1ull << lane) - 1ull));
                const bool sel = pred && (t2 + rank < need);
                float vs = sel ? s_dist[pos] : 0.0f;
                float vm = sel ? s_dist[pos] : -INFINITY;
                #pragma unroll
                for (int m = 1; m < 64; m <<= 1) {
                    vs += __shfl_xor(vs, m);
                    vm = fmaxf(vm, __shfl_xor(vm, m));
                }
                S += vs;
                M = fmaxf(M, vm);
                t2 += cnt;
                if (t2 > need) t2 = need;
            }
        }
        if (lane == 0) {
            s_S[c]   = S;
            s_M[c]   = M;
            s_cnt[c] = total;
        }
    }
    __syncthreads();

    // ---- phase 3: combine classes (trivial, 8 entries) ----
    if (tid == 0) {
        float margin = -INFINITY;
        float pull = 0.0f;
        for (int c = 0; c < NCLS; ++c) {
            if (s_cnt[c] > 0) margin = fmaxf(margin, s_M[c]);
            pull += (float)s_cnt[c] * s_S[c];
            s_hb[c] = 1.0f + s_M[c];
            s_dc[c] = (float)(P - s_cnt[c]);
        }
        s_margin = 1.0f + margin;
        s_pull = pull;
    }
    __syncthreads();

    // ---- phase 4: push term; one point per thread ----
    {
        const float dv = s_dist[tid];
        const int   c  = s_lab[tid];
        const float h  = fmaxf(s_hb[c] - dv, 0.0f);
        float v = (dv < s_margin) ? s_dc[c] * h : 0.0f;
        #pragma unroll
        for (int m = 1; m < 64; m <<= 1) v += __shfl_xor(v, m);
        if (lane == 0) s_wsum[wave] = v;
    }
    __syncthreads();

    if (tid == 0) {
        float t = s_pull;
        #pragma unroll
        for (int w = 0; w < 8; ++w) t += s_wsum[w];
        atomicAdd(out, t * (1.0f / ((float)NSEG * (float)P)));
    }
}

extern "C" void kernel_launch(void* const* d_in, const int* in_sizes, int n_in,
                              void* d_out, int out_size, void* d_ws, size_t ws_size,
                              hipStream_t stream) {
    const float* center  = (const float*)d_in[0];  // (128, 64)
    const float* outputs = (const float*)d_in[1];  // (128, 512, 64)
    const int*   labels  = (const int*)d_in[2];    // (128, 512)
    float* out = (float*)d_out;

    // d_out is poisoned 0xAA before every launch; zero it for the atomicAdd.
    hipMemsetAsync(out, 0, sizeof(float), stream);
    lmnn_kernel<<<dim3(NSEG), dim3(512), 0, stream>>>(center, outputs, labels, out);
}

// Round 2
// 76.686 us; speedup vs baseline: 1.0047x; 1.0047x over previous
//
#include <hip/hip_runtime.h>
#include <math.h>

constexpr int NSEG = 128;
constexpr int P    = 512;
constexpr int D    = 64;
constexpr int KT   = 15;
constexpr int NCLS = 8;

// ---------------- Kernel A: dist_c[seg][pt] = ||outputs - center||^2 -------
// 512 blocks x 256 threads: 4 blocks per segment, each handles 128 points.
// 16 lanes per point (float4 per lane) -> one 4 KB fully-coalesced load per
// block-iteration. All 256 CUs active, 2+ blocks/CU worth of waves in flight.
__global__ __launch_bounds__(256) void dist_kernel(
    const float* __restrict__ center,   // (NSEG, D)
    const float* __restrict__ outputs,  // (NSEG, P, D)
    float* __restrict__ dist)           // (NSEG, P) in d_ws
{
    const int seg     = blockIdx.x >> 2;
    const int quarter = blockIdx.x & 3;
    const int t   = threadIdx.x;
    const int sub = t & 15;    // dim chunk (4 floats)
    const int pg  = t >> 4;    // point within group of 16

    const float4* c4 = reinterpret_cast<const float4*>(center);
    const float4  cf = c4[seg * 16 + sub];

    const float4* o4 = reinterpret_cast<const float4*>(outputs);
    const int pt_base = quarter * 128;

    #pragma unroll
    for (int it = 0; it < 8; ++it) {
        const int pt = pt_base + it * 16 + pg;
        float4 v = o4[((size_t)seg * P + pt) * 16 + sub];
        float dx = v.x - cf.x;
        float dy = v.y - cf.y;
        float dz = v.z - cf.z;
        float dw = v.w - cf.w;
        float acc = dx * dx + dy * dy + dz * dz + dw * dw;
        acc += __shfl_xor(acc, 1);
        acc += __shfl_xor(acc, 2);
        acc += __shfl_xor(acc, 4);
        acc += __shfl_xor(acc, 8);
        if (sub == 0) dist[seg * P + pt] = acc;
    }
}

// ---------------- Kernel B: phases 2-4 on the 256 KB dist array ------------
__global__ __launch_bounds__(512, 1) void combine_kernel(
    const float* __restrict__ dist,     // (NSEG, P) in d_ws
    const int*   __restrict__ labels,   // (NSEG, P)
    float* __restrict__ out)            // scalar
{
    __shared__ float s_dist[P];
    __shared__ int   s_lab[P];
    __shared__ float s_S[NCLS];
    __shared__ float s_M[NCLS];
    __shared__ int   s_cnt[NCLS];
    __shared__ float s_hb[NCLS];   // 1 + M[c]
    __shared__ float s_dc[NCLS];   // P - cnt[c]
    __shared__ float s_margin;
    __shared__ float s_pull;
    __shared__ float s_wsum[8];

    const int seg  = blockIdx.x;
    const int tid  = threadIdx.x;
    const int lane = tid & 63;
    const int wave = tid >> 6;

    s_lab[tid]  = labels[seg * P + tid];
    s_dist[tid] = dist[seg * P + tid];
    __syncthreads();

    // ---- per-class first-15 stats; wave w owns class w ----
    {
        const int c = wave;
        float S = 0.0f;
        float M = -INFINITY;
        int taken = 0;   // selected so far (capped at KT)
        int total = 0;   // full class count
        for (int j = 0; j < 8; ++j) {
            const int pos = j * 64 + lane;
            const bool pred = (s_lab[pos] == c);
            const unsigned long long mask = __ballot(pred);
            const int cnt  = __popcll(mask);
            const int rank = __popcll(mask & ((1ull << lane) - 1ull));
            const bool sel = pred && (taken + rank < KT);
            float vs = sel ? s_dist[pos] : 0.0f;
            float vm = sel ? s_dist[pos] : -INFINITY;
            #pragma unroll
            for (int m = 1; m < 64; m <<= 1) {
                vs += __shfl_xor(vs, m);
                vm = fmaxf(vm, __shfl_xor(vm, m));
            }
            S += vs;
            M = fmaxf(M, vm);
            total += cnt;
            taken += cnt;
            if (taken > KT) taken = KT;
        }
        // Rare: fewer than 15 same-class members -> top_k fills with the
        // lowest-index different-class entries (all tied at -inf).
        if (total < KT) {
            const int need = KT - total;
            int t2 = 0;
            for (int j = 0; j < 8 && t2 < need; ++j) {
                const int pos = j * 64 + lane;
                const bool pred = (s_lab[pos] != c);
                const unsigned long long mask = __ballot(pred);
                const int cnt  = __popcll(mask);
                const int rank = __popcll(mask & ((1ull << lane) - 1ull));
                const bool sel = pred && (t2 + rank < need);
                float vs = sel ? s_dist[pos] : 0.0f;
                float vm = sel ? s_dist[pos] : -INFINITY;
                #pragma unroll
                for (int m = 1; m < 64; m <<= 1) {
                    vs += __shfl_xor(vs, m);
                    vm = fmaxf(vm, __shfl_xor(vm, m));
                }
                S += vs;
                M = fmaxf(M, vm);
                t2 += cnt;
                if (t2 > need) t2 = need;
            }
        }
        if (lane == 0) {
            s_S[c]   = S;
            s_M[c]   = M;
            s_cnt[c] = total;
        }
    }
    __syncthreads();

    // ---- combine classes (8 entries) ----
    if (tid == 0) {
        float margin = -INFINITY;
        float pull = 0.0f;
        for (int c = 0; c < NCLS; ++c) {
            if (s_cnt[c] > 0) margin = fmaxf(margin, s_M[c]);
            pull += (float)s_cnt[c] * s_S[c];
            s_hb[c] = 1.0f + s_M[c];
            s_dc[c] = (float)(P - s_cnt[c]);
        }
        s_margin = 1.0f + margin;
        s_pull = pull;
    }
    __syncthreads();

    // ---- push term; one point per thread ----
    {
        const float dv = s_dist[tid];
        const int   c  = s_lab[tid];
        const float h  = fmaxf(s_hb[c] - dv, 0.0f);
        float v = (dv < s_margin) ? s_dc[c] * h : 0.0f;
        #pragma unroll
        for (int m = 1; m < 64; m <<= 1) v += __shfl_xor(v, m);
        if (lane == 0) s_wsum[wave] = v;
    }
    __syncthreads();

    if (tid == 0) {
        float t = s_pull;
        #pragma unroll
        for (int w = 0; w < 8; ++w) t += s_wsum[w];
        atomicAdd(out, t * (1.0f / ((float)NSEG * (float)P)));
    }
}

extern "C" void kernel_launch(void* const* d_in, const int* in_sizes, int n_in,
                              void* d_out, int out_size, void* d_ws, size_t ws_size,
                              hipStream_t stream) {
    const float* center  = (const float*)d_in[0];  // (128, 64)
    const float* outputs = (const float*)d_in[1];  // (128, 512, 64)
    const int*   labels  = (const int*)d_in[2];    // (128, 512)
    float* out  = (float*)d_out;
    float* dist = (float*)d_ws;                    // 128*512 floats = 256 KB

    // d_out is poisoned 0xAA before every launch; zero it for the atomicAdd.
    hipMemsetAsync(out, 0, sizeof(float), stream);
    dist_kernel<<<dim3(NSEG * 4), dim3(256), 0, stream>>>(center, outputs, dist);
    combine_kernel<<<dim3(NSEG), dim3(512), 0, stream>>>(dist, labels, out);
}